// Round 2
// baseline (334.869 us; speedup 1.0000x reference)
//
#include <hip/hip_runtime.h>
#include <hip/hip_bf16.h>

// Mapper: 4 per-word GEMM layers with LN+LeakyReLU between.
// bf16 MFMA GEMMs (fp32 accumulate), fp32 LN, bf16 activations.
// Round 2: 64x64 tiles for occupancy (latency-bound fix), fused embs cvt,
// XCD-aware swizzle.

typedef unsigned short u16;
typedef __attribute__((ext_vector_type(8))) short bf16x8;
typedef __attribute__((ext_vector_type(4))) float f32x4;

constexpr int CB = 256;      // batch
constexpr int CW = 20;       // words
constexpr int CDIN = 1024;
constexpr int CDOUT = 1024;
constexpr int CH = 1280;
constexpr float CEPS = 1e-5f;
constexpr float CSLOPE = 0.01f;

// fp32 -> bf16 round-to-nearest-even
__device__ __forceinline__ u16 f2bf(float f) {
    union { float f; unsigned u; } v; v.f = f;
    unsigned r = v.u + 0x7fffu + ((v.u >> 16) & 1u);
    return (u16)(r >> 16);
}
__device__ __forceinline__ unsigned pk2(float a, float b) {
    return (unsigned)f2bf(a) | ((unsigned)f2bf(b) << 16);
}

// ---------------------------------------------------------------------------
// GEMM: out[b, w, n] = sum_k A[b, w, k] * Bw[w, k, n] + bias[w, n]
// A: bf16 (u16) or fp32 (AF32), row (b*CW+w), K-contiguous.
// Bw: fp32 [W][K][N]. Out: fp32.
// Tile: BM=64 (over b), BN=64 (over n), BK=32. 256 threads = 4 waves (2x2),
// each wave a 32x32 subtile = 2x2 MFMA 16x16x32 tiles.
// LDS rows K-contiguous, stride 40 u16 (pad 8, keeps 16B align).
// Grid: 4 * (N/64) * CW blocks, XCD-swizzled with mb fastest (weight reuse).
// ---------------------------------------------------------------------------
template <int K, int N, bool AF32>
__global__ __launch_bounds__(256, 6) void gemm_kernel(
    const void* __restrict__ Aptr, const float* __restrict__ Bw,
    const float* __restrict__ bias, float* __restrict__ Out)
{
    constexpr int NB  = N / 64;
    constexpr int NK  = K / 32;
    constexpr int NWG = 4 * NB * CW;
    constexpr int CPX = NWG / 8;

    __shared__ u16 As[2][64 * 40];
    __shared__ u16 Bs[2][64 * 40];

    const int t   = threadIdx.x;
    const int bid = blockIdx.x;
    // XCD swizzle: XCD x owns contiguous logical range [x*CPX, (x+1)*CPX).
    const int logical = (bid & 7) * CPX + (bid >> 3);
    const int mb = logical & 3;
    const int nb = (logical >> 2) % NB;
    const int w  = logical / (4 * NB);

    const int m0g = mb * 64;
    const int n0g = nb * 64;

    const int lane = t & 63;
    const int wid  = t >> 6;
    const int m0 = (wid >> 1) * 32;
    const int n0 = (wid & 1) * 32;
    const int lrow = lane & 15;
    const int kg   = lane >> 4;           // 0..3, k-chunk of 8

    // A staging: thread -> (row = t>>2, k-chunk = (t&3)*8), 16B bf16 / 32B f32
    const int ar = t >> 2;
    const int ac = (t & 3) * 8;
    const u16*   agp  = (const u16*)Aptr   + ((size_t)(m0g + ar) * CW + w) * K + ac;
    const float* agpf = (const float*)Aptr + ((size_t)(m0g + ar) * CW + w) * K + ac;

    // B staging: thread -> (n = t&63, k-chunk = (t>>6)*8), 8 strided dwords
    const int bn = t & 63;
    const int bq = t >> 6;
    const float* bgp = Bw + (size_t)w * K * N + (size_t)bq * 8 * N + (n0g + bn);

    f32x4 acc[2][2];
    #pragma unroll
    for (int i = 0; i < 2; ++i)
        #pragma unroll
        for (int j = 0; j < 2; ++j)
            acc[i][j] = (f32x4){0.f, 0.f, 0.f, 0.f};

    uint4 a0;
    float4 af0, af1;
    float bstg[8];

    auto loadA = [&](int k0) {
        if constexpr (AF32) {
            const float4* p = reinterpret_cast<const float4*>(agpf + k0);
            af0 = p[0]; af1 = p[1];
        } else {
            a0 = *reinterpret_cast<const uint4*>(agp + k0);
        }
    };
    auto loadB = [&](int k0) {
        const float* p = bgp + (size_t)k0 * N;
        #pragma unroll
        for (int i = 0; i < 8; ++i) bstg[i] = p[(size_t)i * N];
    };
    auto writeA = [&](int buf) {
        if constexpr (AF32) {
            uint4 pk;
            pk.x = pk2(af0.x, af0.y); pk.y = pk2(af0.z, af0.w);
            pk.z = pk2(af1.x, af1.y); pk.w = pk2(af1.z, af1.w);
            *reinterpret_cast<uint4*>(&As[buf][ar * 40 + ac]) = pk;
        } else {
            *reinterpret_cast<uint4*>(&As[buf][ar * 40 + ac]) = a0;
        }
    };
    auto writeB = [&](int buf) {
        uint4 pk;
        pk.x = pk2(bstg[0], bstg[1]); pk.y = pk2(bstg[2], bstg[3]);
        pk.z = pk2(bstg[4], bstg[5]); pk.w = pk2(bstg[6], bstg[7]);
        *reinterpret_cast<uint4*>(&Bs[buf][bn * 40 + bq * 8]) = pk;
    };
    auto compute = [&](int buf) {
        bf16x8 af[2], bfr[2];
        #pragma unroll
        for (int i = 0; i < 2; ++i)
            af[i] = *reinterpret_cast<const bf16x8*>(
                &As[buf][(m0 + i * 16 + lrow) * 40 + kg * 8]);
        #pragma unroll
        for (int j = 0; j < 2; ++j)
            bfr[j] = *reinterpret_cast<const bf16x8*>(
                &Bs[buf][(n0 + j * 16 + lrow) * 40 + kg * 8]);
        #pragma unroll
        for (int i = 0; i < 2; ++i)
            #pragma unroll
            for (int j = 0; j < 2; ++j)
                acc[i][j] = __builtin_amdgcn_mfma_f32_16x16x32_bf16(
                    af[i], bfr[j], acc[i][j], 0, 0, 0);
    };

    loadA(0); loadB(0);
    writeA(0); writeB(0);
    __syncthreads();

    int buf = 0;
    for (int ks = 0; ks < NK; ++ks) {
        if (ks + 1 < NK) { loadA((ks + 1) * 32); loadB((ks + 1) * 32); }
        compute(buf);
        if (ks + 1 < NK) { writeA(buf ^ 1); writeB(buf ^ 1); }
        __syncthreads();
        buf ^= 1;
    }

    // epilogue: + bias, store fp32
    const int rb = (lane >> 4) * 4;
    #pragma unroll
    for (int j = 0; j < 2; ++j) {
        const int gn = n0g + n0 + j * 16 + lrow;
        const float bv = bias[(size_t)w * N + gn];
        #pragma unroll
        for (int i = 0; i < 2; ++i) {
            const int gm = m0g + m0 + i * 16 + rb;
            #pragma unroll
            for (int r = 0; r < 4; ++r) {
                Out[((size_t)(gm + r) * CW + w) * N + gn] = acc[i][j][r] + bv;
            }
        }
    }
}

// ---------------------------------------------------------------------------
// LayerNorm + LeakyReLU over last dim (H=1280), writes bf16.
// One block (320 threads, 5 waves) per row; each thread one float4.
// ---------------------------------------------------------------------------
__global__ __launch_bounds__(320) void ln_lrelu_kernel(
    const float* __restrict__ h, const float* __restrict__ g,
    const float* __restrict__ bta, u16* __restrict__ out)
{
    const int row = blockIdx.x;          // b*CW + w
    const int w = row % CW;
    const int t = threadIdx.x;

    const float4 v = reinterpret_cast<const float4*>(h + (size_t)row * CH)[t];
    float s  = v.x + v.y + v.z + v.w;
    float sq = v.x * v.x + v.y * v.y + v.z * v.z + v.w * v.w;
    #pragma unroll
    for (int o = 32; o > 0; o >>= 1) {
        s  += __shfl_down(s, o, 64);
        sq += __shfl_down(sq, o, 64);
    }
    __shared__ float ss[5], sg[5];
    const int lane = t & 63, wv = t >> 6;
    if (lane == 0) { ss[wv] = s; sg[wv] = sq; }
    __syncthreads();
    float S = 0.f, Q = 0.f;
    #pragma unroll
    for (int i = 0; i < 5; ++i) { S += ss[i]; Q += sg[i]; }
    const float mean = S * (1.0f / CH);
    const float var  = Q * (1.0f / CH) - mean * mean;
    const float rstd = rsqrtf(var + CEPS);

    const float4 gg = reinterpret_cast<const float4*>(g   + (size_t)w * CH)[t];
    const float4 bb = reinterpret_cast<const float4*>(bta + (size_t)w * CH)[t];
    float4 y;
    y.x = (v.x - mean) * rstd * gg.x + bb.x;
    y.y = (v.y - mean) * rstd * gg.y + bb.y;
    y.z = (v.z - mean) * rstd * gg.z + bb.z;
    y.w = (v.w - mean) * rstd * gg.w + bb.w;
    y.x = y.x >= 0.f ? y.x : CSLOPE * y.x;
    y.y = y.y >= 0.f ? y.y : CSLOPE * y.y;
    y.z = y.z >= 0.f ? y.z : CSLOPE * y.z;
    y.w = y.w >= 0.f ? y.w : CSLOPE * y.w;
    ushort4 o4;
    o4.x = f2bf(y.x); o4.y = f2bf(y.y); o4.z = f2bf(y.z); o4.w = f2bf(y.w);
    reinterpret_cast<ushort4*>(out + (size_t)row * CH)[t] = o4;
}

extern "C" void kernel_launch(void* const* d_in, const int* in_sizes, int n_in,
                              void* d_out, int out_size, void* d_ws, size_t ws_size,
                              hipStream_t stream)
{
    const float* embs = (const float*)d_in[0];
    const float* W1  = (const float*)d_in[1];
    const float* b1  = (const float*)d_in[2];
    const float* g1  = (const float*)d_in[3];
    const float* bn1 = (const float*)d_in[4];
    const float* W2  = (const float*)d_in[5];
    const float* b2  = (const float*)d_in[6];
    const float* g2  = (const float*)d_in[7];
    const float* bn2 = (const float*)d_in[8];
    const float* W3  = (const float*)d_in[9];
    const float* b3  = (const float*)d_in[10];
    const float* g3  = (const float*)d_in[11];
    const float* bn3 = (const float*)d_in[12];
    const float* W4  = (const float*)d_in[13];
    const float* b4  = (const float*)d_in[14];

    char* ws = (char*)d_ws;
    float* h_raw = (float*)ws;                               // B*W*H*4  = 26,214,400
    u16*   a_bf  = (u16*)(ws + 26214400);                    // B*W*H*2  = 13,107,200

    // Layer 1: [256x1024] @ [1024x1280], A = embs fp32 (converted in staging)
    gemm_kernel<CDIN, CH, true><<<4 * (CH / 64) * CW, 256, 0, stream>>>(embs, W1, b1, h_raw);
    ln_lrelu_kernel<<<CB * CW, 320, 0, stream>>>(h_raw, g1, bn1, a_bf);
    // Layer 2: [256x1280] @ [1280x1280]
    gemm_kernel<CH, CH, false><<<4 * (CH / 64) * CW, 256, 0, stream>>>(a_bf, W2, b2, h_raw);
    ln_lrelu_kernel<<<CB * CW, 320, 0, stream>>>(h_raw, g2, bn2, a_bf);
    // Layer 3: [256x1280] @ [1280x1280]
    gemm_kernel<CH, CH, false><<<4 * (CH / 64) * CW, 256, 0, stream>>>(a_bf, W3, b3, h_raw);
    ln_lrelu_kernel<<<CB * CW, 320, 0, stream>>>(h_raw, g3, bn3, a_bf);
    // Layer 4: [256x1280] @ [1280x1024] -> d_out (fp32)
    gemm_kernel<CH, CDOUT, false><<<4 * (CDOUT / 64) * CW, 256, 0, stream>>>(a_bf, W4, b4, (float*)d_out);
}